// Round 8
// baseline (788.071 us; speedup 1.0000x reference)
//
#include <hip/hip_runtime.h>
#include <cmath>

// ---------------------------------------------------------------------------
// TimestepVisionTransformer — Round 7: conv-L1 as NHWC f16 MFMA island +
// patch embed as f16 MFMA. L2/L3/final convs stay r5-measured k_convg.
// B=128, IMG=224, P=16, C_IN=1, E=96, H=4, d=24, NAX=14, N=196, M=B*N=25088
// ---------------------------------------------------------------------------

#define B_   128
#define NPATCH 196
#define M_ROWS (B_*NPATCH)     // 25088
#define E_   96
#define KS   4
#define SEG  49

typedef _Float16 half8 __attribute__((ext_vector_type(8)));
typedef _Float16 half4v __attribute__((ext_vector_type(4)));
typedef float f32x4 __attribute__((ext_vector_type(4)));

// ---------------------------------------------------------------------------
// time embedding
// ---------------------------------------------------------------------------
__global__ void k_time(const float* __restrict__ ts,
                       const float* __restrict__ Wt1, const float* __restrict__ bt1,
                       const float* __restrict__ Wt2, const float* __restrict__ bt2,
                       float* __restrict__ timev)
{
    __shared__ float h[128];
    float e = 0.69314718055994530942f * ts[0];
    float sv = sinf(e), cv = cosf(e);
    int t = threadIdx.x;
    float z = sv * Wt1[t] + cv * Wt1[128 + t] + bt1[t];
    h[t] = z / (1.f + expf(-z));
    __syncthreads();
    if (t < 96) {
        float acc = bt2[t];
        for (int j = 0; j < 128; ++j) acc += h[j] * Wt2[j * 96 + t];
        timev[t] = acc;
    }
}

// ---------------------------------------------------------------------------
// weight repack for convT layers 2..4 into per-parity float4 taps (fp32).
// (L1 slice [0,73728) is written then overwritten by k_wcvtc — unused.)
// ---------------------------------------------------------------------------
__global__ void __launch_bounds__(256) k_repack(const float* __restrict__ w1,
                                                const float* __restrict__ w2,
                                                const float* __restrict__ w3,
                                                const float* __restrict__ w4f,
                                                float* __restrict__ wr)
{
    int i = blockIdx.x * 256 + threadIdx.x;
    const float* src; int CIN, COUT, e; float* dst;
    if      (i < 73728) { src = w1;  CIN = 96; COUT = 48; e = i;          dst = wr; }
    else if (i < 92160) { src = w2;  CIN = 48; COUT = 24; e = i - 73728;  dst = wr + 73728; }
    else if (i < 96768) { src = w3;  CIN = 24; COUT = 12; e = i - 92160;  dst = wr + 92160; }
    else if (i < 96960) { src = w4f; CIN = 12; COUT = 1;  e = i - 96768;  dst = wr + 96768; }
    else return;
    int per = CIN * COUT * 4;
    int par = e / per, rem = e % per;
    int ci = rem / (COUT * 4);
    int o  = (rem >> 2) % COUT;
    int j  = rem & 3;
    int ry = par >> 1, rx = par & 1;
    int wy = (j < 2)  ? (3 - ry) : (1 - ry);
    int wx = (j & 1)  ? (1 - rx) : (3 - rx);
    dst[e] = src[(ci * COUT + o) * 16 + wy * 4 + wx];
}

// ---------------------------------------------------------------------------
// conv1 weights -> f16 B-layout Wc[p][o][k=tap*96+ci], tap order matches
// k_convg (x,y,z,w) = (0,0),(0,1),(1,0),(1,1).
// ---------------------------------------------------------------------------
__global__ void __launch_bounds__(256) k_wcvtc(const float* __restrict__ w1,
                                               _Float16* __restrict__ wc)
{
    int i = blockIdx.x * 256 + threadIdx.x;
    if (i >= 4 * 48 * 384) return;
    int p = i / 18432, rem = i % 18432;
    int o = rem / 384, k = rem % 384;
    int tap = k / 96, ci = k % 96;
    int ry = p >> 1, rx = p & 1;
    int wy = (tap < 2) ? (3 - ry) : (1 - ry);
    int wx = (tap & 1) ? (1 - rx) : (3 - rx);
    wc[i] = (_Float16)w1[(ci * 48 + o) * 16 + wy * 4 + wx];
}

// ---------------------------------------------------------------------------
// transformer weight convert+transpose to half: Wt[n][k] = W[k][n]
// ---------------------------------------------------------------------------
__global__ void __launch_bounds__(256) k_wcvt(const float* __restrict__ qkv0,
                                              const float* __restrict__ qkv1,
                                              const float* __restrict__ wo0,
                                              const float* __restrict__ wo1,
                                              const float* __restrict__ wm0,
                                              const float* __restrict__ wm1,
                                              const float* __restrict__ wm2,
                                              _Float16* __restrict__ wh)
{
    int i = blockIdx.x * 256 + threadIdx.x;
    const float* src; int N; int e;
    if      (i < 27648)  { src = qkv0; N = 288; e = i; }
    else if (i < 55296)  { src = qkv1; N = 288; e = i - 27648; }
    else if (i < 64512)  { src = wo0;  N = 96;  e = i - 55296; }
    else if (i < 73728)  { src = wo1;  N = 96;  e = i - 64512; }
    else if (i < 82944)  { src = wm0;  N = 96;  e = i - 73728; }
    else if (i < 92160)  { src = wm1;  N = 96;  e = i - 82944; }
    else if (i < 101376) { src = wm2;  N = 96;  e = i - 92160; }
    else return;
    int n = e / 96, k = e % 96;
    wh[i] = (_Float16)src[k * N + n];
}

// ---------------------------------------------------------------------------
// zero the borders of xinh NHWC f16 [b][16][16][96] (interior by MLP3)
// ---------------------------------------------------------------------------
__global__ void __launch_bounds__(256) k_zb_h(_Float16* __restrict__ xinh)
{
    int i = blockIdx.x * 256 + threadIdx.x;
    if (i >= 128 * 60 * 96) return;
    int b = i / 5760, r = i % 5760;
    int pos = r / 96, ch = r % 96;
    int py, px;
    if      (pos < 16) { py = 0;        px = pos; }
    else if (pos < 32) { py = 15;       px = pos - 16; }
    else if (pos < 46) { py = pos - 31; px = 0; }
    else               { py = pos - 45; px = 15; }
    xinh[((size_t)(b * 256) + py * 16 + px) * 96 + ch] = (_Float16)0.f;
}

// ---------------------------------------------------------------------------
// patch embed GEMM via f16 MFMA: [25088 x 256] @ WpT[256 x 96] + bias + RoPE.
// 64 patches/block, K in 2 chunks of 128. RoPE pairs via __shfl_xor(.,1).
// ---------------------------------------------------------------------------
__global__ void __launch_bounds__(256) k_patch_mfma(const float* __restrict__ x,
                                                    const float* __restrict__ Wp,
                                                    const float* __restrict__ bp,
                                                    float* __restrict__ out)
{
    __shared__ __align__(16) _Float16 Ah[64 * 136];
    __shared__ __align__(16) _Float16 Wh[96 * 136];
    int t = threadIdx.x;
    int p0 = blockIdx.x * 64;
    int wave = t >> 6, lane = t & 63;
    int lm = lane & 15, quad = lane >> 4;
    f32x4 acc[6];
    #pragma unroll
    for (int nt = 0; nt < 6; ++nt) acc[nt] = (f32x4){0.f, 0.f, 0.f, 0.f};

    for (int kc = 0; kc < 2; ++kc) {
        __syncthreads();
        // stage A: 64 patches x 128 k (k = (kc*8+pyl)*16+px)
        for (int i = t; i < 512; i += 256) {
            int lp = i >> 3, pyl = i & 7;
            int patch = p0 + lp;
            int b = patch / NPATCH, n = patch % NPATCH;
            int ny = n / 14, nx = n % 14;
            const float4* s4 = (const float4*)(x +
                ((size_t)(b * 224) + ny * 16 + kc * 8 + pyl) * 224 + nx * 16);
            float4 v0 = s4[0], v1 = s4[1], v2 = s4[2], v3 = s4[3];
            half8 h0, h1;
            h0[0]=(_Float16)v0.x; h0[1]=(_Float16)v0.y; h0[2]=(_Float16)v0.z; h0[3]=(_Float16)v0.w;
            h0[4]=(_Float16)v1.x; h0[5]=(_Float16)v1.y; h0[6]=(_Float16)v1.z; h0[7]=(_Float16)v1.w;
            h1[0]=(_Float16)v2.x; h1[1]=(_Float16)v2.y; h1[2]=(_Float16)v2.z; h1[3]=(_Float16)v2.w;
            h1[4]=(_Float16)v3.x; h1[5]=(_Float16)v3.y; h1[6]=(_Float16)v3.z; h1[7]=(_Float16)v3.w;
            *(half8*)&Ah[lp * 136 + pyl * 16]     = h0;
            *(half8*)&Ah[lp * 136 + pyl * 16 + 8] = h1;
        }
        // stage W chunk: Wh[e][kl] = Wp[e*256 + kc*128 + kl]
        for (int i = t; i < 1536; i += 256) {
            int e = i >> 4, s = i & 15;
            const float4* s4 = (const float4*)(Wp + e * 256 + kc * 128 + s * 8);
            float4 v0 = s4[0], v1 = s4[1];
            half8 h0;
            h0[0]=(_Float16)v0.x; h0[1]=(_Float16)v0.y; h0[2]=(_Float16)v0.z; h0[3]=(_Float16)v0.w;
            h0[4]=(_Float16)v1.x; h0[5]=(_Float16)v1.y; h0[6]=(_Float16)v1.z; h0[7]=(_Float16)v1.w;
            *(half8*)&Wh[e * 136 + s * 8] = h0;
        }
        __syncthreads();
        half8 af[4];
        #pragma unroll
        for (int ks = 0; ks < 4; ++ks)
            af[ks] = *(const half8*)&Ah[(wave * 16 + lm) * 136 + ks * 32 + quad * 8];
        #pragma unroll
        for (int ks = 0; ks < 4; ++ks) {
            #pragma unroll
            for (int nt = 0; nt < 6; ++nt) {
                half8 bf = *(const half8*)&Wh[(nt * 16 + lm) * 136 + ks * 32 + quad * 8];
                acc[nt] = __builtin_amdgcn_mfma_f32_16x16x32_f16(af[ks], bf, acc[nt], 0, 0, 0);
            }
        }
    }

    // epilogue: bias + RoPE (pairs across adjacent lanes) + write [patch][e]
    #pragma unroll
    for (int nt = 0; nt < 6; ++nt) {
        #pragma unroll
        for (int r = 0; r < 4; ++r) {
            int e = nt * 16 + lm;
            int lp = wave * 16 + quad * 4 + r;
            int patch = p0 + lp;
            int n = patch % NPATCH;
            int ny = n / 14, nx = n % 14;
            float yx = (float)(ny + nx);
            float v = acc[nt][r] + bp[e];
            float other = __shfl_xor(v, 1);
            float fi = (float)(e >> 1);
            float theta = expf(fi * (-2.f / 96.f) * 9.210340371976184f);
            float ang = theta * yx;
            float c = cosf(ang), s = sinf(ang);
            float outv = (lm & 1) ? (other * s + v * c) : (v * c - other * s);
            out[(size_t)patch * 96 + e] = outv;
        }
    }
}

// ---------------------------------------------------------------------------
// row LayerNorm over 96, wave per row
// ---------------------------------------------------------------------------
__global__ void __launch_bounds__(256) k_ln_row(const float* __restrict__ x,
                                                const float* __restrict__ g,
                                                const float* __restrict__ bv,
                                                float* __restrict__ out, int M)
{
    int lane = threadIdx.x & 63;
    int gw = (blockIdx.x * 256 + threadIdx.x) >> 6;
    int nw = (gridDim.x * 256) >> 6;
    float g0 = g[lane], b0 = bv[lane];
    float g1 = 0.f, b1 = 0.f;
    if (lane < 32) { g1 = g[64 + lane]; b1 = bv[64 + lane]; }
    for (int r = gw; r < M; r += nw) {
        const float* xr = x + (size_t)r * 96;
        float a = xr[lane];
        float c = (lane < 32) ? xr[64 + lane] : 0.f;
        float s = a + c, q = a * a + c * c;
        #pragma unroll
        for (int off = 32; off; off >>= 1) {
            s += __shfl_xor(s, off);
            q += __shfl_xor(q, off);
        }
        float mu = s * (1.f / 96.f);
        float rstd = rsqrtf(q * (1.f / 96.f) - mu * mu + 1e-5f);
        float* orow = out + (size_t)r * 96;
        orow[lane] = (a - mu) * rstd * g0 + b0;
        if (lane < 32) orow[64 + lane] = (c - mu) * rstd * g1 + b1;
    }
}

// ---------------------------------------------------------------------------
// MFMA row GEMM (as r6, verified). OUTH: write f16 NHWC padded xinh instead.
// ---------------------------------------------------------------------------
template<int NCHUNKS, bool SILU, bool RES, bool ADDTIME, bool OUTH>
__global__ void __launch_bounds__(256) k_gemm_mfma(const float* __restrict__ A,
                                                   const _Float16* __restrict__ Wt,
                                                   const float* __restrict__ bias,
                                                   const float* __restrict__ res,
                                                   const float* __restrict__ timev,
                                                   float* __restrict__ out,
                                                   _Float16* __restrict__ outh)
{
    __shared__ __align__(16) _Float16 Ah[64 * 96];
    __shared__ __align__(16) _Float16 Wh[96 * 96];
    constexpr int NTOT = NCHUNKS * 96;
    int t = threadIdx.x;
    size_t row0 = (size_t)blockIdx.x * 64;

    const float4* a4 = (const float4*)(A + row0 * 96);
    for (int i = t; i < 1536; i += 256) {
        float4 v = a4[i];
        half4v hv;
        hv[0] = (_Float16)v.x; hv[1] = (_Float16)v.y;
        hv[2] = (_Float16)v.z; hv[3] = (_Float16)v.w;
        *(half4v*)&Ah[i * 4] = hv;
    }

    int wave = t >> 6, lane = t & 63;
    int lm = lane & 15, quad = lane >> 4;
    const f32x4 vzero = {0.f, 0.f, 0.f, 0.f};

    for (int ch = 0; ch < NCHUNKS; ++ch) {
        __syncthreads();
        {
            const uint4* src = (const uint4*)(Wt + (size_t)ch * 9216);
            uint4* dst = (uint4*)Wh;
            for (int i = t; i < 1152; i += 256) dst[i] = src[i];
        }
        __syncthreads();

        half8 af[3];
        #pragma unroll
        for (int ks = 0; ks < 3; ++ks)
            af[ks] = *(const half8*)&Ah[(wave * 16 + lm) * 96 + ks * 32 + quad * 8];

        f32x4 acc[6];
        #pragma unroll
        for (int ct = 0; ct < 6; ++ct) acc[ct] = vzero;

        #pragma unroll
        for (int ct = 0; ct < 6; ++ct) {
            #pragma unroll
            for (int ks = 0; ks < 3; ++ks) {
                half8 bf = *(const half8*)&Wh[(ct * 16 + lm) * 96 + ks * 32 + quad * 8];
                acc[ct] = __builtin_amdgcn_mfma_f32_16x16x32_f16(af[ks], bf, acc[ct], 0, 0, 0);
            }
        }

        #pragma unroll
        for (int ct = 0; ct < 6; ++ct) {
            #pragma unroll
            for (int r = 0; r < 4; ++r) {
                int lr = wave * 16 + quad * 4 + r;
                size_t row = row0 + lr;
                int lc = ct * 16 + lm;
                int col = ch * 96 + lc;
                float v = acc[ct][r] + bias[col];
                if constexpr (RES)     v += res[row * 96 + lc];
                if constexpr (ADDTIME) v += timev[lc];
                if constexpr (SILU)    v = v / (1.f + expf(-v));
                if constexpr (OUTH) {
                    size_t b = row / NPATCH; int n = (int)(row % NPATCH);
                    int ny = n / 14, nx = n % 14;
                    outh[((b * 256) + (1 + ny) * 16 + (1 + nx)) * 96 + col] = (_Float16)v;
                } else {
                    out[row * NTOT + col] = v;
                }
            }
        }
    }
}

// ---------------------------------------------------------------------------
// attention partials (r4, verified)
// ---------------------------------------------------------------------------
__global__ void __launch_bounds__(256) k_attn_part(const float* __restrict__ qkv,
                                                   float* __restrict__ part)
{
    int blk = blockIdx.x;
    int seg = blk % KS;
    int bh  = blk / KS;
    int b = bh >> 2, h = bh & 3;
    const float* base = qkv + (size_t)b * NPATCH * 288 + h * 24;
    __shared__ __align__(16) float KV[SEG * 48];
    int t = threadIdx.x;
    int k0 = seg * SEG;
    for (int i = t; i < SEG * 48; i += 256) {
        int k = i / 48, j = i % 48;
        KV[i] = base[(size_t)(k0 + k) * 288 + 96 + (j < 24 ? j : j + 72)];
    }
    __syncthreads();

    int q = (t < NPATCH) ? t : 0;
    float qv[24], acc[24];
    const float4* qrow = (const float4*)(base + (size_t)q * 288);
    #pragma unroll
    for (int j = 0; j < 6; ++j) {
        float4 v = qrow[j];
        qv[4 * j] = v.x; qv[4 * j + 1] = v.y; qv[4 * j + 2] = v.z; qv[4 * j + 3] = v.w;
    }
    #pragma unroll
    for (int d = 0; d < 24; ++d) acc[d] = 0.f;
    float sum = 0.f;
    const float scale = 0.2041241452319315f;

    #pragma unroll 2
    for (int k = 0; k < SEG; ++k) {
        const float4* kr = (const float4*)(&KV[k * 48]);
        float s0 = 0.f, s1 = 0.f, s2 = 0.f, s3 = 0.f;
        #pragma unroll
        for (int j = 0; j < 6; ++j) {
            float4 Kv = kr[j];
            s0 += qv[4 * j]     * Kv.x;
            s1 += qv[4 * j + 1] * Kv.y;
            s2 += qv[4 * j + 2] * Kv.z;
            s3 += qv[4 * j + 3] * Kv.w;
        }
        float s = (s0 + s1) + (s2 + s3);
        float p = __expf(fminf(s * scale, 60.f));
        sum += p;
        #pragma unroll
        for (int j = 0; j < 6; ++j) {
            float4 Vv = kr[6 + j];
            acc[4 * j]     += p * Vv.x;
            acc[4 * j + 1] += p * Vv.y;
            acc[4 * j + 2] += p * Vv.z;
            acc[4 * j + 3] += p * Vv.w;
        }
    }

    if (t < NPATCH) {
        float4* pp = (float4*)(part + ((size_t)blk * NPATCH + t) * 28);
        #pragma unroll
        for (int j = 0; j < 6; ++j) {
            float4 v;
            v.x = acc[4 * j]; v.y = acc[4 * j + 1];
            v.z = acc[4 * j + 2]; v.w = acc[4 * j + 3];
            pp[j] = v;
        }
        float4 sv; sv.x = sum; sv.y = 0.f; sv.z = 0.f; sv.w = 0.f;
        pp[6] = sv;
    }
}

// ---------------------------------------------------------------------------
// combine K-split partials
// ---------------------------------------------------------------------------
__global__ void __launch_bounds__(256) k_attn_comb(const float* __restrict__ part,
                                                   float* __restrict__ o)
{
    int idx = blockIdx.x * 256 + threadIdx.x;
    int bh = idx / NPATCH, q = idx % NPATCH;
    int b = bh >> 2, h = bh & 3;
    float acc[24];
    #pragma unroll
    for (int d = 0; d < 24; ++d) acc[d] = 0.f;
    float sum = 0.f;
    #pragma unroll
    for (int s = 0; s < KS; ++s) {
        const float4* pp = (const float4*)(part + ((size_t)(bh * KS + s) * NPATCH + q) * 28);
        #pragma unroll
        for (int j = 0; j < 6; ++j) {
            float4 v = pp[j];
            acc[4 * j]     += v.x;
            acc[4 * j + 1] += v.y;
            acc[4 * j + 2] += v.z;
            acc[4 * j + 3] += v.w;
        }
        sum += pp[6].x;
    }
    float inv = 1.f / sum;
    float4* orow = (float4*)(o + ((size_t)b * NPATCH + q) * 96 + h * 24);
    #pragma unroll
    for (int j = 0; j < 6; ++j) {
        float4 v;
        v.x = acc[4 * j] * inv; v.y = acc[4 * j + 1] * inv;
        v.z = acc[4 * j + 2] * inv; v.w = acc[4 * j + 3] * inv;
        orow[j] = v;
    }
}

// ---------------------------------------------------------------------------
// conv L1 via MFMA: input xinh NHWC f16 padded [b][16][16][96].
// Block = 64 pixels (b-major). Per parity p=(ry,rx): im2col A[64][384] in
// LDS (row stride 392: 2-way-free banks); B from Wc[p][o][384] (global,
// L2-hot); out C1 NHWC fp32 [b][28][28][48] + bias.
// Tap t=(i,j): A[..][t*96+ci] = xinh[b][py+ry+i][px+rx+j][ci]  (k_convg map).
// ---------------------------------------------------------------------------
__global__ void __launch_bounds__(256) k_conv1(const _Float16* __restrict__ xinh,
                                               const _Float16* __restrict__ wc,
                                               const float* __restrict__ bias,
                                               float* __restrict__ c1)
{
    __shared__ __align__(16) _Float16 Ah[64 * 392];
    int t = threadIdx.x;
    int blk = blockIdx.x;
    int wave = t >> 6, lane = t & 63;
    int lm = lane & 15, quad = lane >> 4;

    for (int p = 0; p < 4; ++p) {
        int ry = p >> 1, rx = p & 1;
        __syncthreads();   // protect Ah reuse across parities
        for (int i = t; i < 64 * 48; i += 256) {
            int lp = i / 48, rem = i % 48;          // rem*8 = k offset in halves
            int tap = rem / 12;
            int gp = blk * 64 + lp;
            int b = gp / NPATCH, pix = gp % NPATCH;
            int py = pix / 14, px = pix % 14;
            int row = py + ry + (tap >> 1), col = px + rx + (tap & 1);
            const uint4* src = (const uint4*)(xinh +
                ((size_t)(b * 256) + row * 16 + col) * 96 + (rem % 12) * 8);
            *(uint4*)&Ah[lp * 392 + rem * 8] = *src;
        }
        __syncthreads();

        half8 af[12];
        #pragma unroll
        for (int ks = 0; ks < 12; ++ks)
            af[ks] = *(const half8*)&Ah[(wave * 16 + lm) * 392 + ks * 32 + quad * 8];

        f32x4 acc[3];
        #pragma unroll
        for (int nt = 0; nt < 3; ++nt) acc[nt] = (f32x4){0.f, 0.f, 0.f, 0.f};

        #pragma unroll
        for (int ks = 0; ks < 12; ++ks) {
            #pragma unroll
            for (int nt = 0; nt < 3; ++nt) {
                half8 bf = *(const half8*)&wc[((size_t)(p * 48 + nt * 16 + lm)) * 384
                                              + ks * 32 + quad * 8];
                acc[nt] = __builtin_amdgcn_mfma_f32_16x16x32_f16(af[ks], bf, acc[nt], 0, 0, 0);
            }
        }

        #pragma unroll
        for (int nt = 0; nt < 3; ++nt) {
            #pragma unroll
            for (int r = 0; r < 4; ++r) {
                int o = nt * 16 + lm;
                int lp = wave * 16 + quad * 4 + r;
                int gp = blk * 64 + lp;
                int b = gp / NPATCH, pix = gp % NPATCH;
                int py = pix / 14, px = pix % 14;
                int oy = 2 * py + ry, ox = 2 * px + rx;
                c1[((size_t)(b * 28 + oy) * 28 + ox) * 48 + o] = acc[nt][r] + bias[o];
            }
        }
    }
}

// ---------------------------------------------------------------------------
// spatial LN on NHWC C1 [b][28][28][48] -> planar padded XP2 [b*48][30][30]
// block = (b, half of channels): grid 256.
// ---------------------------------------------------------------------------
__global__ void __launch_bounds__(256) k_ln_pad_nhwc(const float* __restrict__ c1,
                                                     const float* __restrict__ g,
                                                     const float* __restrict__ bv,
                                                     float* __restrict__ xp)
{
    int b = blockIdx.x >> 1;
    int cg = (blockIdx.x & 1) * 24;
    int t = threadIdx.x;
    __shared__ float sred[240], qred[240];
    __shared__ float smu[24], srs[24];
    int ch = t % 24, grp = t / 24;
    if (t < 240) {
        float s = 0.f, q = 0.f;
        for (int pix = grp; pix < 784; pix += 10) {
            float v = c1[((size_t)b * 784 + pix) * 48 + cg + ch];
            s += v; q += v * v;
        }
        sred[t] = s; qred[t] = q;
    }
    __syncthreads();
    if (t < 24) {
        float ss = 0.f, qq = 0.f;
        for (int gi = 0; gi < 10; ++gi) { ss += sred[gi * 24 + t]; qq += qred[gi * 24 + t]; }
        float mu = ss * (1.f / 784.f);
        smu[t] = mu;
        srs[t] = rsqrtf(qq * (1.f / 784.f) - mu * mu + 1e-5f);
    }
    __syncthreads();
    for (int i = t; i < 24 * 900; i += 256) {
        int c = i / 900, pos = i % 900;
        int pyp = pos / 30, pxp = pos % 30;
        float v = 0.f;
        if (pyp >= 1 && pyp <= 28 && pxp >= 1 && pxp <= 28) {
            int j = (pyp - 1) * 28 + (pxp - 1);
            float u = (c1[((size_t)b * 784 + j) * 48 + cg + c] - smu[c]) * srs[c] * g[j] + bv[j];
            v = u / (1.f + expf(-u));
        }
        xp[((size_t)(b * 48) + cg + c) * 900 + pos] = v;
    }
}

// ---------------------------------------------------------------------------
// transposed conv (planar, r5-measured config) — L2 & L3
// ---------------------------------------------------------------------------
template<int CIN, int HIN, int COUT, int G>
__global__ void __launch_bounds__(256) k_convg(const float* __restrict__ xp,
                                               const float* __restrict__ wr,
                                               const float* __restrict__ bias,
                                               float* __restrict__ out)
{
    constexpr int HP = HIN + 2;
    constexpr int HO = 2 * HIN;
    constexpr int NPB = (B_ * HIN * HIN) / 256;
    int pb = blockIdx.x % NPB;
    int z  = blockIdx.x / NPB;
    int og = z % (COUT / G);
    int ry = z / (COUT / G);
    int o0 = og * G;
    int rem = pb * 256 + threadIdx.x;
    int b   = rem / (HIN * HIN);
    int pix = rem % (HIN * HIN);
    int py = pix / HIN, px = pix % HIN;
    const float* xb = xp + ((size_t)b * CIN) * (HP * HP) + (py + ry) * HP + px;
    const float4* w4 = (const float4*)wr;
    float acc0[G], acc1[G];
    #pragma unroll
    for (int o = 0; o < G; ++o) { acc0[o] = 0.f; acc1[o] = 0.f; }
    float f00 = xb[0], f01 = xb[1], f02 = xb[2];
    float f10 = xb[HP], f11 = xb[HP + 1], f12 = xb[HP + 2];
    for (int ci = 0; ci < CIN; ++ci) {
        int cn = (ci + 1 < CIN) ? (ci + 1) : (CIN - 1);
        const float* xn = xb + (size_t)cn * (HP * HP);
        float n00 = xn[0], n01 = xn[1], n02 = xn[2];
        float n10 = xn[HP], n11 = xn[HP + 1], n12 = xn[HP + 2];
        const float4* w0 = w4 + ((size_t)(2 * ry) * CIN + ci) * COUT + o0;
        const float4* w1 = w0 + (size_t)CIN * COUT;
        #pragma unroll
        for (int o = 0; o < G; ++o) {
            float4 W0 = w0[o], W1 = w1[o];
            acc0[o] += f00 * W0.x + f01 * W0.y + f10 * W0.z + f11 * W0.w;
            acc1[o] += f01 * W1.x + f02 * W1.y + f11 * W1.z + f12 * W1.w;
        }
        f00 = n00; f01 = n01; f02 = n02; f10 = n10; f11 = n11; f12 = n12;
    }
    int oy = 2 * py + ry;
    #pragma unroll
    for (int o = 0; o < G; ++o) {
        float bb = bias[o0 + o];
        float2 v; v.x = acc0[o] + bb; v.y = acc1[o] + bb;
        *(float2*)(out + ((size_t)(b * COUT + o0 + o) * HO + oy) * HO + 2 * px) = v;
    }
}

// ---------------------------------------------------------------------------
// spatial LN planar -> planar padded (L2 output)
// ---------------------------------------------------------------------------
template<int H>
__global__ void __launch_bounds__(256) k_ln_pad(const float* __restrict__ cin,
                                                const float* __restrict__ g,
                                                const float* __restrict__ bv,
                                                float* __restrict__ xp)
{
    constexpr int HW = H * H;
    constexpr int HP = H + 2;
    constexpr int HWP = HP * HP;
    size_t plane = blockIdx.x;
    const float* src = cin + plane * HW;
    float* dst = xp + plane * HWP;
    int t = threadIdx.x;
    float s = 0.f, q = 0.f;
    for (int i = t; i < HW; i += 256) {
        float v = src[i];
        s += v; q += v * v;
    }
    #pragma unroll
    for (int off = 32; off; off >>= 1) {
        s += __shfl_xor(s, off);
        q += __shfl_xor(q, off);
    }
    __shared__ float rs[8];
    int wave = t >> 6, lane = t & 63;
    if (lane == 0) { rs[wave] = s; rs[4 + wave] = q; }
    __syncthreads();
    float st = rs[0] + rs[1] + rs[2] + rs[3];
    float qt = rs[4] + rs[5] + rs[6] + rs[7];
    float mu = st / (float)HW;
    float rstd = rsqrtf(qt / (float)HW - mu * mu + 1e-5f);
    for (int i = t; i < HWP; i += 256) {
        int py = i / HP, px = i % HP;
        float v = 0.f;
        if (py >= 1 && py <= H && px >= 1 && px <= H) {
            int j = (py - 1) * H + (px - 1);
            float u = (src[j] - mu) * rstd * g[j] + bv[j];
            v = u / (1.f + expf(-u));
        }
        dst[i] = v;
    }
}

// ---------------------------------------------------------------------------
// in-place spatial LN + affine + silu (L3 output)
// ---------------------------------------------------------------------------
template<int HW>
__global__ void __launch_bounds__(256) k_ln_spatial(float* __restrict__ f,
                                                    const float* __restrict__ g,
                                                    const float* __restrict__ bv)
{
    size_t base = (size_t)blockIdx.x * HW;
    int t = threadIdx.x;
    float s = 0.f, q = 0.f;
    for (int i = t; i < HW; i += 256) {
        float v = f[base + i];
        s += v; q += v * v;
    }
    #pragma unroll
    for (int off = 32; off; off >>= 1) {
        s += __shfl_xor(s, off);
        q += __shfl_xor(q, off);
    }
    __shared__ float rs[8];
    int wave = t >> 6, lane = t & 63;
    if (lane == 0) { rs[wave] = s; rs[4 + wave] = q; }
    __syncthreads();
    float st = rs[0] + rs[1] + rs[2] + rs[3];
    float qt = rs[4] + rs[5] + rs[6] + rs[7];
    float mu = st / (float)HW;
    float rstd = rsqrtf(qt / (float)HW - mu * mu + 1e-5f);
    for (int i = t; i < HW; i += 256) {
        float v = (f[base + i] - mu) * rstd * g[i] + bv[i];
        f[base + i] = v / (1.f + expf(-v));
    }
}

// ---------------------------------------------------------------------------
// final convT 12->1 (r4-measured 2-parity version)
// ---------------------------------------------------------------------------
__global__ void __launch_bounds__(256) k_conv_final(const float* __restrict__ x,
                                                    const float* __restrict__ wr,
                                                    const float* __restrict__ bias,
                                                    float* __restrict__ out)
{
    constexpr int HIN = 112, CIN = 12, HP2 = 12544;
    constexpr int NPB = (B_ * HIN * HIN) / 256;
    int pb = blockIdx.x % NPB;
    int ry = blockIdx.x / NPB;
    int rem = pb * 256 + threadIdx.x;
    int b   = rem / (HIN * HIN);
    int pix = rem % (HIN * HIN);
    int py = pix / HIN, px = pix % HIN;
    int r0 = py + ry - 1, r1 = r0 + 1;
    bool my0 = r0 >= 0, my1 = r1 < HIN;
    bool mx0 = px >= 1, mx2 = px + 1 < HIN;
    const float* xb = x + (size_t)b * CIN * HP2;
    const float4* w4 = (const float4*)wr;
    float acc0 = 0.f, acc1 = 0.f;
    #pragma unroll
    for (int ci = 0; ci < CIN; ++ci) {
        const float* xc = xb + ci * HP2;
        const float* xr0 = xc + r0 * HIN + px;
        const float* xr1 = xc + r1 * HIN + px;
        float g00 = (my0 && mx0) ? xr0[-1] : 0.f;
        float g01 = my0 ? xr0[0] : 0.f;
        float g02 = (my0 && mx2) ? xr0[1] : 0.f;
        float g10 = (my1 && mx0) ? xr1[-1] : 0.f;
        float g11 = my1 ? xr1[0] : 0.f;
        float g12 = (my1 && mx2) ? xr1[1] : 0.f;
        float4 W0 = w4[(2 * ry) * CIN + ci];
        float4 W1 = w4[(2 * ry + 1) * CIN + ci];
        acc0 += g00 * W0.x + g01 * W0.y + g10 * W0.z + g11 * W0.w;
        acc1 += g01 * W1.x + g02 * W1.y + g11 * W1.z + g12 * W1.w;
    }
    float bb = bias[0];
    float u0 = acc0 + bb, u1 = acc1 + bb;
    u0 = u0 / (1.f + expf(-u0));
    u1 = u1 / (1.f + expf(-u1));
    float2 v;
    v.x = fminf(fmaxf(u0, 0.f), 1.f);
    v.y = fminf(fmaxf(u1, 0.f), 1.f);
    int oy = 2 * py + ry;
    *(float2*)(out + (size_t)b * 50176 + oy * 224 + 2 * px) = v;
}

// ---------------------------------------------------------------------------
// launch
// ---------------------------------------------------------------------------
extern "C" void kernel_launch(void* const* d_in, const int* in_sizes, int n_in,
                              void* d_out, int out_size, void* d_ws, size_t ws_size,
                              hipStream_t stream)
{
    const float* x       = (const float*)d_in[0];
    const float* ts      = (const float*)d_in[1];
    const float* Wp      = (const float*)d_in[2];
    const float* bp      = (const float*)d_in[3];
    const float* Wt1     = (const float*)d_in[4];
    const float* bt1     = (const float*)d_in[5];
    const float* Wt2     = (const float*)d_in[6];
    const float* bt2     = (const float*)d_in[7];
    const float* a0_g    = (const float*)d_in[8];
    const float* a0_b    = (const float*)d_in[9];
    const float* a0_Wqkv = (const float*)d_in[10];
    const float* a0_bqkv = (const float*)d_in[11];
    const float* a0_Wo   = (const float*)d_in[12];
    const float* a0_bo   = (const float*)d_in[13];
    const float* a1_g    = (const float*)d_in[14];
    const float* a1_b    = (const float*)d_in[15];
    const float* a1_Wqkv = (const float*)d_in[16];
    const float* a1_bqkv = (const float*)d_in[17];
    const float* a1_Wo   = (const float*)d_in[18];
    const float* a1_bo   = (const float*)d_in[19];
    const float* Wm0     = (const float*)d_in[20];
    const float* bm0     = (const float*)d_in[21];
    const float* Wm1     = (const float*)d_in[22];
    const float* bm1     = (const float*)d_in[23];
    const float* Wm2     = (const float*)d_in[24];
    const float* bm2     = (const float*)d_in[25];
    const float* Wd1     = (const float*)d_in[26];
    const float* bd1     = (const float*)d_in[27];
    const float* l1g     = (const float*)d_in[28];
    const float* l1b     = (const float*)d_in[29];
    const float* Wd2     = (const float*)d_in[30];
    const float* bd2     = (const float*)d_in[31];
    const float* l2g     = (const float*)d_in[32];
    const float* l2b     = (const float*)d_in[33];
    const float* Wd3     = (const float*)d_in[34];
    const float* bd3     = (const float*)d_in[35];
    const float* l3g     = (const float*)d_in[36];
    const float* l3b     = (const float*)d_in[37];
    const float* Wd4     = (const float*)d_in[38];
    const float* bd4     = (const float*)d_in[39];
    float* out = (float*)d_out;

    // arena (floats); R = 25088*96
    const size_t R = 2408448;
    float* ws   = (float*)d_ws;
    float* tvec = ws;                          // 96
    float* p0   = ws + 512;                    // R
    float* h    = ws + 512 + R;                // R
    float* qkvb = ws + 512 + 2 * R;            // 3R
    float* ob   = ws + 512 + 5 * R;            // R
    float* p1   = ws + 512 + 6 * R;            // R
    float* part = ws + 512 + 7 * R;            // attn partials (aliases XP2/XP3)
    // decoder aliases:
    _Float16* xinh = (_Float16*)(ws + 512 + 2 * R);   // f16 NHWC [b][16][16][96] (qkv region)
    float* C1   = ws + 512 + 5 * R;            // NHWC fp32 [b][28][28][48] = 2R (ob+p1)
    float* XP2  = ws + 512 + 7 * R;            // planar padded [b*48][30][30]
    float* C2   = ws + 512;                    // (p0..qkv regions)
    float* XP3  = ws + 512 + 7 * R + 5529600;
    float* C3   = ws + 512;                    // (p0..XP2 regions)
    float* Wr   = ws + 512 + 7 * R + 5529600 + 10334208;  // 96,960 floats
    _Float16* WH = (_Float16*)(Wr + 96960);                // 101,376 halves
    _Float16* Wc = (_Float16*)Wr;              // conv1 f16 B-weights (73,728 halves,
                                               // overwrites dead L1 slice of Wr)
    const size_t NEED = (512 + 7 * R + 5529600 + 10334208 + 96960 + 50688 + 16)
                        * sizeof(float);
    if (ws_size < NEED) return;

    _Float16* WHqkv0 = WH;
    _Float16* WHqkv1 = WH + 27648;
    _Float16* WHwo0  = WH + 55296;
    _Float16* WHwo1  = WH + 64512;
    _Float16* WHwm0  = WH + 73728;
    _Float16* WHwm1  = WH + 82944;
    _Float16* WHwm2  = WH + 92160;

    k_time<<<1, 128, 0, stream>>>(ts, Wt1, bt1, Wt2, bt2, tvec);
    k_repack<<<379, 256, 0, stream>>>(Wd1, Wd2, Wd3, Wd4, Wr);
    k_wcvtc<<<288, 256, 0, stream>>>(Wd1, Wc);   // after k_repack (same region)
    k_wcvt<<<396, 256, 0, stream>>>(a0_Wqkv, a1_Wqkv, a0_Wo, a1_Wo,
                                    Wm0, Wm1, Wm2, WH);
    k_patch_mfma<<<M_ROWS / 64, 256, 0, stream>>>(x, Wp, bp, p0);

    // MHSA block 0
    k_ln_row<<<1024, 256, 0, stream>>>(p0, a0_g, a0_b, h, M_ROWS);
    k_gemm_mfma<3, false, false, false, false><<<M_ROWS / 64, 256, 0, stream>>>(
        h, WHqkv0, a0_bqkv, nullptr, nullptr, qkvb, nullptr);
    k_attn_part<<<B_ * 4 * KS, 256, 0, stream>>>(qkvb, part);
    k_attn_comb<<<(B_ * 4 * NPATCH) / 256, 256, 0, stream>>>(part, ob);
    k_gemm_mfma<1, false, true, false, false><<<M_ROWS / 64, 256, 0, stream>>>(
        ob, WHwo0, a0_bo, p0, nullptr, p1, nullptr);

    // MHSA block 1 (+time)
    k_ln_row<<<1024, 256, 0, stream>>>(p1, a1_g, a1_b, h, M_ROWS);
    k_gemm_mfma<3, false, false, false, false><<<M_ROWS / 64, 256, 0, stream>>>(
        h, WHqkv1, a1_bqkv, nullptr, nullptr, qkvb, nullptr);
    k_attn_part<<<B_ * 4 * KS, 256, 0, stream>>>(qkvb, part);
    k_attn_comb<<<(B_ * 4 * NPATCH) / 256, 256, 0, stream>>>(part, ob);
    k_gemm_mfma<1, false, true, true, false><<<M_ROWS / 64, 256, 0, stream>>>(
        ob, WHwo1, a1_bo, p1, tvec, p0, nullptr);

    // qkv region free: zero xinh borders before MLP3 writes interior
    k_zb_h<<<2880, 256, 0, stream>>>(xinh);

    // MLP x3 (silu); last writes f16 NHWC padded xinh
    k_gemm_mfma<1, true, false, false, false><<<M_ROWS / 64, 256, 0, stream>>>(
        p0, WHwm0, bm0, nullptr, nullptr, p1, nullptr);
    k_gemm_mfma<1, true, false, false, false><<<M_ROWS / 64, 256, 0, stream>>>(
        p1, WHwm1, bm1, nullptr, nullptr, p0, nullptr);
    k_gemm_mfma<1, true, false, false, true><<<M_ROWS / 64, 256, 0, stream>>>(
        p0, WHwm2, bm2, nullptr, nullptr, nullptr, xinh);

    // decoder: L1 MFMA, then r5-measured planar convs
    k_conv1<<<M_ROWS / 64, 256, 0, stream>>>(xinh, Wc, bd1, C1);
    k_ln_pad_nhwc<<<B_ * 2, 256, 0, stream>>>(C1, l1g, l1b, XP2);
    k_convg<48, 28, 24, 8><<<2 * 3 * 392, 256, 0, stream>>>(XP2, Wr + 73728, bd2, C2);
    k_ln_pad<56><<<B_ * 24, 256, 0, stream>>>(C2, l2g, l2b, XP3);
    k_convg<24, 56, 12, 12><<<2 * 1 * 1568, 256, 0, stream>>>(XP3, Wr + 92160, bd3, C3);
    k_ln_spatial<12544><<<B_ * 12, 256, 0, stream>>>(C3, l3g, l3b);
    k_conv_final<<<2 * 6272, 256, 0, stream>>>(C3, Wr + 96768, bd4, out);
}

// Round 9
// 738.840 us; speedup vs baseline: 1.0666x; 1.0666x over previous
//
#include <hip/hip_runtime.h>
#include <cmath>

// ---------------------------------------------------------------------------
// TimestepVisionTransformer — Round 8: replace the serial ln_pad_nhwc bridge
// with parallel stats+apply kernels. Everything else = r7 (verified).
// B=128, IMG=224, P=16, C_IN=1, E=96, H=4, d=24, NAX=14, N=196, M=B*N=25088
// ---------------------------------------------------------------------------

#define B_   128
#define NPATCH 196
#define M_ROWS (B_*NPATCH)     // 25088
#define E_   96
#define KS   4
#define SEG  49

typedef _Float16 half8 __attribute__((ext_vector_type(8)));
typedef _Float16 half4v __attribute__((ext_vector_type(4)));
typedef float f32x4 __attribute__((ext_vector_type(4)));

// ---------------------------------------------------------------------------
// time embedding
// ---------------------------------------------------------------------------
__global__ void k_time(const float* __restrict__ ts,
                       const float* __restrict__ Wt1, const float* __restrict__ bt1,
                       const float* __restrict__ Wt2, const float* __restrict__ bt2,
                       float* __restrict__ timev)
{
    __shared__ float h[128];
    float e = 0.69314718055994530942f * ts[0];
    float sv = sinf(e), cv = cosf(e);
    int t = threadIdx.x;
    float z = sv * Wt1[t] + cv * Wt1[128 + t] + bt1[t];
    h[t] = z / (1.f + expf(-z));
    __syncthreads();
    if (t < 96) {
        float acc = bt2[t];
        for (int j = 0; j < 128; ++j) acc += h[j] * Wt2[j * 96 + t];
        timev[t] = acc;
    }
}

// ---------------------------------------------------------------------------
// weight repack for convT layers 2..4 into per-parity float4 taps (fp32).
// (L1 slice [0,73728) is overwritten by k_wcvtc — unused.)
// ---------------------------------------------------------------------------
__global__ void __launch_bounds__(256) k_repack(const float* __restrict__ w1,
                                                const float* __restrict__ w2,
                                                const float* __restrict__ w3,
                                                const float* __restrict__ w4f,
                                                float* __restrict__ wr)
{
    int i = blockIdx.x * 256 + threadIdx.x;
    const float* src; int CIN, COUT, e; float* dst;
    if      (i < 73728) { src = w1;  CIN = 96; COUT = 48; e = i;          dst = wr; }
    else if (i < 92160) { src = w2;  CIN = 48; COUT = 24; e = i - 73728;  dst = wr + 73728; }
    else if (i < 96768) { src = w3;  CIN = 24; COUT = 12; e = i - 92160;  dst = wr + 92160; }
    else if (i < 96960) { src = w4f; CIN = 12; COUT = 1;  e = i - 96768;  dst = wr + 96768; }
    else return;
    int per = CIN * COUT * 4;
    int par = e / per, rem = e % per;
    int ci = rem / (COUT * 4);
    int o  = (rem >> 2) % COUT;
    int j  = rem & 3;
    int ry = par >> 1, rx = par & 1;
    int wy = (j < 2)  ? (3 - ry) : (1 - ry);
    int wx = (j & 1)  ? (1 - rx) : (3 - rx);
    dst[e] = src[(ci * COUT + o) * 16 + wy * 4 + wx];
}

// ---------------------------------------------------------------------------
// conv1 weights -> f16 B-layout Wc[p][o][k=tap*96+ci]
// ---------------------------------------------------------------------------
__global__ void __launch_bounds__(256) k_wcvtc(const float* __restrict__ w1,
                                               _Float16* __restrict__ wc)
{
    int i = blockIdx.x * 256 + threadIdx.x;
    if (i >= 4 * 48 * 384) return;
    int p = i / 18432, rem = i % 18432;
    int o = rem / 384, k = rem % 384;
    int tap = k / 96, ci = k % 96;
    int ry = p >> 1, rx = p & 1;
    int wy = (tap < 2) ? (3 - ry) : (1 - ry);
    int wx = (tap & 1) ? (1 - rx) : (3 - rx);
    wc[i] = (_Float16)w1[(ci * 48 + o) * 16 + wy * 4 + wx];
}

// ---------------------------------------------------------------------------
// transformer weight convert+transpose to half: Wt[n][k] = W[k][n]
// ---------------------------------------------------------------------------
__global__ void __launch_bounds__(256) k_wcvt(const float* __restrict__ qkv0,
                                              const float* __restrict__ qkv1,
                                              const float* __restrict__ wo0,
                                              const float* __restrict__ wo1,
                                              const float* __restrict__ wm0,
                                              const float* __restrict__ wm1,
                                              const float* __restrict__ wm2,
                                              _Float16* __restrict__ wh)
{
    int i = blockIdx.x * 256 + threadIdx.x;
    const float* src; int N; int e;
    if      (i < 27648)  { src = qkv0; N = 288; e = i; }
    else if (i < 55296)  { src = qkv1; N = 288; e = i - 27648; }
    else if (i < 64512)  { src = wo0;  N = 96;  e = i - 55296; }
    else if (i < 73728)  { src = wo1;  N = 96;  e = i - 64512; }
    else if (i < 82944)  { src = wm0;  N = 96;  e = i - 73728; }
    else if (i < 92160)  { src = wm1;  N = 96;  e = i - 82944; }
    else if (i < 101376) { src = wm2;  N = 96;  e = i - 92160; }
    else return;
    int n = e / 96, k = e % 96;
    wh[i] = (_Float16)src[k * N + n];
}

// ---------------------------------------------------------------------------
// zero the borders of xinh NHWC f16 [b][16][16][96]
// ---------------------------------------------------------------------------
__global__ void __launch_bounds__(256) k_zb_h(_Float16* __restrict__ xinh)
{
    int i = blockIdx.x * 256 + threadIdx.x;
    if (i >= 128 * 60 * 96) return;
    int b = i / 5760, r = i % 5760;
    int pos = r / 96, ch = r % 96;
    int py, px;
    if      (pos < 16) { py = 0;        px = pos; }
    else if (pos < 32) { py = 15;       px = pos - 16; }
    else if (pos < 46) { py = pos - 31; px = 0; }
    else               { py = pos - 45; px = 15; }
    xinh[((size_t)(b * 256) + py * 16 + px) * 96 + ch] = (_Float16)0.f;
}

// ---------------------------------------------------------------------------
// patch embed GEMM via f16 MFMA (r7, verified)
// ---------------------------------------------------------------------------
__global__ void __launch_bounds__(256) k_patch_mfma(const float* __restrict__ x,
                                                    const float* __restrict__ Wp,
                                                    const float* __restrict__ bp,
                                                    float* __restrict__ out)
{
    __shared__ __align__(16) _Float16 Ah[64 * 136];
    __shared__ __align__(16) _Float16 Wh[96 * 136];
    int t = threadIdx.x;
    int p0 = blockIdx.x * 64;
    int wave = t >> 6, lane = t & 63;
    int lm = lane & 15, quad = lane >> 4;
    f32x4 acc[6];
    #pragma unroll
    for (int nt = 0; nt < 6; ++nt) acc[nt] = (f32x4){0.f, 0.f, 0.f, 0.f};

    for (int kc = 0; kc < 2; ++kc) {
        __syncthreads();
        for (int i = t; i < 512; i += 256) {
            int lp = i >> 3, pyl = i & 7;
            int patch = p0 + lp;
            int b = patch / NPATCH, n = patch % NPATCH;
            int ny = n / 14, nx = n % 14;
            const float4* s4 = (const float4*)(x +
                ((size_t)(b * 224) + ny * 16 + kc * 8 + pyl) * 224 + nx * 16);
            float4 v0 = s4[0], v1 = s4[1], v2 = s4[2], v3 = s4[3];
            half8 h0, h1;
            h0[0]=(_Float16)v0.x; h0[1]=(_Float16)v0.y; h0[2]=(_Float16)v0.z; h0[3]=(_Float16)v0.w;
            h0[4]=(_Float16)v1.x; h0[5]=(_Float16)v1.y; h0[6]=(_Float16)v1.z; h0[7]=(_Float16)v1.w;
            h1[0]=(_Float16)v2.x; h1[1]=(_Float16)v2.y; h1[2]=(_Float16)v2.z; h1[3]=(_Float16)v2.w;
            h1[4]=(_Float16)v3.x; h1[5]=(_Float16)v3.y; h1[6]=(_Float16)v3.z; h1[7]=(_Float16)v3.w;
            *(half8*)&Ah[lp * 136 + pyl * 16]     = h0;
            *(half8*)&Ah[lp * 136 + pyl * 16 + 8] = h1;
        }
        for (int i = t; i < 1536; i += 256) {
            int e = i >> 4, s = i & 15;
            const float4* s4 = (const float4*)(Wp + e * 256 + kc * 128 + s * 8);
            float4 v0 = s4[0], v1 = s4[1];
            half8 h0;
            h0[0]=(_Float16)v0.x; h0[1]=(_Float16)v0.y; h0[2]=(_Float16)v0.z; h0[3]=(_Float16)v0.w;
            h0[4]=(_Float16)v1.x; h0[5]=(_Float16)v1.y; h0[6]=(_Float16)v1.z; h0[7]=(_Float16)v1.w;
            *(half8*)&Wh[e * 136 + s * 8] = h0;
        }
        __syncthreads();
        half8 af[4];
        #pragma unroll
        for (int ks = 0; ks < 4; ++ks)
            af[ks] = *(const half8*)&Ah[(wave * 16 + lm) * 136 + ks * 32 + quad * 8];
        #pragma unroll
        for (int ks = 0; ks < 4; ++ks) {
            #pragma unroll
            for (int nt = 0; nt < 6; ++nt) {
                half8 bf = *(const half8*)&Wh[(nt * 16 + lm) * 136 + ks * 32 + quad * 8];
                acc[nt] = __builtin_amdgcn_mfma_f32_16x16x32_f16(af[ks], bf, acc[nt], 0, 0, 0);
            }
        }
    }

    #pragma unroll
    for (int nt = 0; nt < 6; ++nt) {
        #pragma unroll
        for (int r = 0; r < 4; ++r) {
            int e = nt * 16 + lm;
            int lp = wave * 16 + quad * 4 + r;
            int patch = p0 + lp;
            int n = patch % NPATCH;
            int ny = n / 14, nx = n % 14;
            float yx = (float)(ny + nx);
            float v = acc[nt][r] + bp[e];
            float other = __shfl_xor(v, 1);
            float fi = (float)(e >> 1);
            float theta = expf(fi * (-2.f / 96.f) * 9.210340371976184f);
            float ang = theta * yx;
            float c = cosf(ang), s = sinf(ang);
            float outv = (lm & 1) ? (other * s + v * c) : (v * c - other * s);
            out[(size_t)patch * 96 + e] = outv;
        }
    }
}

// ---------------------------------------------------------------------------
// row LayerNorm over 96, wave per row
// ---------------------------------------------------------------------------
__global__ void __launch_bounds__(256) k_ln_row(const float* __restrict__ x,
                                                const float* __restrict__ g,
                                                const float* __restrict__ bv,
                                                float* __restrict__ out, int M)
{
    int lane = threadIdx.x & 63;
    int gw = (blockIdx.x * 256 + threadIdx.x) >> 6;
    int nw = (gridDim.x * 256) >> 6;
    float g0 = g[lane], b0 = bv[lane];
    float g1 = 0.f, b1 = 0.f;
    if (lane < 32) { g1 = g[64 + lane]; b1 = bv[64 + lane]; }
    for (int r = gw; r < M; r += nw) {
        const float* xr = x + (size_t)r * 96;
        float a = xr[lane];
        float c = (lane < 32) ? xr[64 + lane] : 0.f;
        float s = a + c, q = a * a + c * c;
        #pragma unroll
        for (int off = 32; off; off >>= 1) {
            s += __shfl_xor(s, off);
            q += __shfl_xor(q, off);
        }
        float mu = s * (1.f / 96.f);
        float rstd = rsqrtf(q * (1.f / 96.f) - mu * mu + 1e-5f);
        float* orow = out + (size_t)r * 96;
        orow[lane] = (a - mu) * rstd * g0 + b0;
        if (lane < 32) orow[64 + lane] = (c - mu) * rstd * g1 + b1;
    }
}

// ---------------------------------------------------------------------------
// MFMA row GEMM (r6, verified). OUTH: write f16 NHWC padded xinh instead.
// ---------------------------------------------------------------------------
template<int NCHUNKS, bool SILU, bool RES, bool ADDTIME, bool OUTH>
__global__ void __launch_bounds__(256) k_gemm_mfma(const float* __restrict__ A,
                                                   const _Float16* __restrict__ Wt,
                                                   const float* __restrict__ bias,
                                                   const float* __restrict__ res,
                                                   const float* __restrict__ timev,
                                                   float* __restrict__ out,
                                                   _Float16* __restrict__ outh)
{
    __shared__ __align__(16) _Float16 Ah[64 * 96];
    __shared__ __align__(16) _Float16 Wh[96 * 96];
    constexpr int NTOT = NCHUNKS * 96;
    int t = threadIdx.x;
    size_t row0 = (size_t)blockIdx.x * 64;

    const float4* a4 = (const float4*)(A + row0 * 96);
    for (int i = t; i < 1536; i += 256) {
        float4 v = a4[i];
        half4v hv;
        hv[0] = (_Float16)v.x; hv[1] = (_Float16)v.y;
        hv[2] = (_Float16)v.z; hv[3] = (_Float16)v.w;
        *(half4v*)&Ah[i * 4] = hv;
    }

    int wave = t >> 6, lane = t & 63;
    int lm = lane & 15, quad = lane >> 4;
    const f32x4 vzero = {0.f, 0.f, 0.f, 0.f};

    for (int ch = 0; ch < NCHUNKS; ++ch) {
        __syncthreads();
        {
            const uint4* src = (const uint4*)(Wt + (size_t)ch * 9216);
            uint4* dst = (uint4*)Wh;
            for (int i = t; i < 1152; i += 256) dst[i] = src[i];
        }
        __syncthreads();

        half8 af[3];
        #pragma unroll
        for (int ks = 0; ks < 3; ++ks)
            af[ks] = *(const half8*)&Ah[(wave * 16 + lm) * 96 + ks * 32 + quad * 8];

        f32x4 acc[6];
        #pragma unroll
        for (int ct = 0; ct < 6; ++ct) acc[ct] = vzero;

        #pragma unroll
        for (int ct = 0; ct < 6; ++ct) {
            #pragma unroll
            for (int ks = 0; ks < 3; ++ks) {
                half8 bf = *(const half8*)&Wh[(ct * 16 + lm) * 96 + ks * 32 + quad * 8];
                acc[ct] = __builtin_amdgcn_mfma_f32_16x16x32_f16(af[ks], bf, acc[ct], 0, 0, 0);
            }
        }

        #pragma unroll
        for (int ct = 0; ct < 6; ++ct) {
            #pragma unroll
            for (int r = 0; r < 4; ++r) {
                int lr = wave * 16 + quad * 4 + r;
                size_t row = row0 + lr;
                int lc = ct * 16 + lm;
                int col = ch * 96 + lc;
                float v = acc[ct][r] + bias[col];
                if constexpr (RES)     v += res[row * 96 + lc];
                if constexpr (ADDTIME) v += timev[lc];
                if constexpr (SILU)    v = v / (1.f + expf(-v));
                if constexpr (OUTH) {
                    size_t b = row / NPATCH; int n = (int)(row % NPATCH);
                    int ny = n / 14, nx = n % 14;
                    outh[((b * 256) + (1 + ny) * 16 + (1 + nx)) * 96 + col] = (_Float16)v;
                } else {
                    out[row * NTOT + col] = v;
                }
            }
        }
    }
}

// ---------------------------------------------------------------------------
// attention partials (r4, verified)
// ---------------------------------------------------------------------------
__global__ void __launch_bounds__(256) k_attn_part(const float* __restrict__ qkv,
                                                   float* __restrict__ part)
{
    int blk = blockIdx.x;
    int seg = blk % KS;
    int bh  = blk / KS;
    int b = bh >> 2, h = bh & 3;
    const float* base = qkv + (size_t)b * NPATCH * 288 + h * 24;
    __shared__ __align__(16) float KV[SEG * 48];
    int t = threadIdx.x;
    int k0 = seg * SEG;
    for (int i = t; i < SEG * 48; i += 256) {
        int k = i / 48, j = i % 48;
        KV[i] = base[(size_t)(k0 + k) * 288 + 96 + (j < 24 ? j : j + 72)];
    }
    __syncthreads();

    int q = (t < NPATCH) ? t : 0;
    float qv[24], acc[24];
    const float4* qrow = (const float4*)(base + (size_t)q * 288);
    #pragma unroll
    for (int j = 0; j < 6; ++j) {
        float4 v = qrow[j];
        qv[4 * j] = v.x; qv[4 * j + 1] = v.y; qv[4 * j + 2] = v.z; qv[4 * j + 3] = v.w;
    }
    #pragma unroll
    for (int d = 0; d < 24; ++d) acc[d] = 0.f;
    float sum = 0.f;
    const float scale = 0.2041241452319315f;

    #pragma unroll 2
    for (int k = 0; k < SEG; ++k) {
        const float4* kr = (const float4*)(&KV[k * 48]);
        float s0 = 0.f, s1 = 0.f, s2 = 0.f, s3 = 0.f;
        #pragma unroll
        for (int j = 0; j < 6; ++j) {
            float4 Kv = kr[j];
            s0 += qv[4 * j]     * Kv.x;
            s1 += qv[4 * j + 1] * Kv.y;
            s2 += qv[4 * j + 2] * Kv.z;
            s3 += qv[4 * j + 3] * Kv.w;
        }
        float s = (s0 + s1) + (s2 + s3);
        float p = __expf(fminf(s * scale, 60.f));
        sum += p;
        #pragma unroll
        for (int j = 0; j < 6; ++j) {
            float4 Vv = kr[6 + j];
            acc[4 * j]     += p * Vv.x;
            acc[4 * j + 1] += p * Vv.y;
            acc[4 * j + 2] += p * Vv.z;
            acc[4 * j + 3] += p * Vv.w;
        }
    }

    if (t < NPATCH) {
        float4* pp = (float4*)(part + ((size_t)blk * NPATCH + t) * 28);
        #pragma unroll
        for (int j = 0; j < 6; ++j) {
            float4 v;
            v.x = acc[4 * j]; v.y = acc[4 * j + 1];
            v.z = acc[4 * j + 2]; v.w = acc[4 * j + 3];
            pp[j] = v;
        }
        float4 sv; sv.x = sum; sv.y = 0.f; sv.z = 0.f; sv.w = 0.f;
        pp[6] = sv;
    }
}

// ---------------------------------------------------------------------------
// combine K-split partials
// ---------------------------------------------------------------------------
__global__ void __launch_bounds__(256) k_attn_comb(const float* __restrict__ part,
                                                   float* __restrict__ o)
{
    int idx = blockIdx.x * 256 + threadIdx.x;
    int bh = idx / NPATCH, q = idx % NPATCH;
    int b = bh >> 2, h = bh & 3;
    float acc[24];
    #pragma unroll
    for (int d = 0; d < 24; ++d) acc[d] = 0.f;
    float sum = 0.f;
    #pragma unroll
    for (int s = 0; s < KS; ++s) {
        const float4* pp = (const float4*)(part + ((size_t)(bh * KS + s) * NPATCH + q) * 28);
        #pragma unroll
        for (int j = 0; j < 6; ++j) {
            float4 v = pp[j];
            acc[4 * j]     += v.x;
            acc[4 * j + 1] += v.y;
            acc[4 * j + 2] += v.z;
            acc[4 * j + 3] += v.w;
        }
        sum += pp[6].x;
    }
    float inv = 1.f / sum;
    float4* orow = (float4*)(o + ((size_t)b * NPATCH + q) * 96 + h * 24);
    #pragma unroll
    for (int j = 0; j < 6; ++j) {
        float4 v;
        v.x = acc[4 * j] * inv; v.y = acc[4 * j + 1] * inv;
        v.z = acc[4 * j + 2] * inv; v.w = acc[4 * j + 3] * inv;
        orow[j] = v;
    }
}

// ---------------------------------------------------------------------------
// conv L1 via MFMA (r7, verified): xinh NHWC f16 padded -> C1 NHWC fp32
// ---------------------------------------------------------------------------
__global__ void __launch_bounds__(256) k_conv1(const _Float16* __restrict__ xinh,
                                               const _Float16* __restrict__ wc,
                                               const float* __restrict__ bias,
                                               float* __restrict__ c1)
{
    __shared__ __align__(16) _Float16 Ah[64 * 392];
    int t = threadIdx.x;
    int blk = blockIdx.x;
    int wave = t >> 6, lane = t & 63;
    int lm = lane & 15, quad = lane >> 4;

    for (int p = 0; p < 4; ++p) {
        int ry = p >> 1, rx = p & 1;
        __syncthreads();
        for (int i = t; i < 64 * 48; i += 256) {
            int lp = i / 48, rem = i % 48;
            int tap = rem / 12;
            int gp = blk * 64 + lp;
            int b = gp / NPATCH, pix = gp % NPATCH;
            int py = pix / 14, px = pix % 14;
            int row = py + ry + (tap >> 1), col = px + rx + (tap & 1);
            const uint4* src = (const uint4*)(xinh +
                ((size_t)(b * 256) + row * 16 + col) * 96 + (rem % 12) * 8);
            *(uint4*)&Ah[lp * 392 + rem * 8] = *src;
        }
        __syncthreads();

        half8 af[12];
        #pragma unroll
        for (int ks = 0; ks < 12; ++ks)
            af[ks] = *(const half8*)&Ah[(wave * 16 + lm) * 392 + ks * 32 + quad * 8];

        f32x4 acc[3];
        #pragma unroll
        for (int nt = 0; nt < 3; ++nt) acc[nt] = (f32x4){0.f, 0.f, 0.f, 0.f};

        #pragma unroll
        for (int ks = 0; ks < 12; ++ks) {
            #pragma unroll
            for (int nt = 0; nt < 3; ++nt) {
                half8 bf = *(const half8*)&wc[((size_t)(p * 48 + nt * 16 + lm)) * 384
                                              + ks * 32 + quad * 8];
                acc[nt] = __builtin_amdgcn_mfma_f32_16x16x32_f16(af[ks], bf, acc[nt], 0, 0, 0);
            }
        }

        #pragma unroll
        for (int nt = 0; nt < 3; ++nt) {
            #pragma unroll
            for (int r = 0; r < 4; ++r) {
                int o = nt * 16 + lm;
                int lp = wave * 16 + quad * 4 + r;
                int gp = blk * 64 + lp;
                int b = gp / NPATCH, pix = gp % NPATCH;
                int py = pix / 14, px = pix % 14;
                int oy = 2 * py + ry, ox = 2 * px + rx;
                c1[((size_t)(b * 28 + oy) * 28 + ox) * 48 + o] = acc[nt][r] + bias[o];
            }
        }
    }
}

// ---------------------------------------------------------------------------
// L1 LN stats: one wave per (b,ch) over NHWC C1 -> stat[b*48+ch] = {mu,rstd}
// grid 1536 x 256 (4 waves/block).
// ---------------------------------------------------------------------------
__global__ void __launch_bounds__(256) k_ln1_stats(const float* __restrict__ c1,
                                                   float* __restrict__ stat)
{
    int idx = blockIdx.x * 4 + (threadIdx.x >> 6);   // b*48+ch
    int lane = threadIdx.x & 63;
    int b = idx / 48, ch = idx % 48;
    const float* base = c1 + (size_t)b * 784 * 48 + ch;
    float s = 0.f, q = 0.f;
    for (int pix = lane; pix < 784; pix += 64) {
        float v = base[(size_t)pix * 48];
        s += v; q += v * v;
    }
    #pragma unroll
    for (int off = 32; off; off >>= 1) {
        s += __shfl_xor(s, off);
        q += __shfl_xor(q, off);
    }
    if (lane == 0) {
        float mu = s * (1.f / 784.f);
        float rstd = rsqrtf(q * (1.f / 784.f) - mu * mu + 1e-5f);
        stat[idx * 2]     = mu;
        stat[idx * 2 + 1] = rstd;
    }
}

// ---------------------------------------------------------------------------
// L1 LN apply: NHWC C1 + stat -> planar padded XP2 [b*48][30][30], silu.
// one thread per padded element; grid 21600.
// ---------------------------------------------------------------------------
__global__ void __launch_bounds__(256) k_ln1_apply(const float* __restrict__ c1,
                                                   const float* __restrict__ stat,
                                                   const float* __restrict__ g,
                                                   const float* __restrict__ bv,
                                                   float* __restrict__ xp)
{
    int i = blockIdx.x * 256 + threadIdx.x;          // plane*900 + pos
    if (i >= 6144 * 900) return;
    int plane = i / 900, pos = i % 900;
    int b = plane / 48, ch = plane % 48;
    int py = pos / 30, px = pos % 30;
    float v = 0.f;
    if (py >= 1 && py <= 28 && px >= 1 && px <= 28) {
        int j = (py - 1) * 28 + (px - 1);
        float mu = stat[plane * 2], rstd = stat[plane * 2 + 1];
        float u = (c1[((size_t)b * 784 + j) * 48 + ch] - mu) * rstd * g[j] + bv[j];
        v = u / (1.f + expf(-u));
    }
    xp[(size_t)plane * 900 + pos] = v;
}

// ---------------------------------------------------------------------------
// transposed conv (planar, r5-measured config) — L2 & L3
// ---------------------------------------------------------------------------
template<int CIN, int HIN, int COUT, int G>
__global__ void __launch_bounds__(256) k_convg(const float* __restrict__ xp,
                                               const float* __restrict__ wr,
                                               const float* __restrict__ bias,
                                               float* __restrict__ out)
{
    constexpr int HP = HIN + 2;
    constexpr int HO = 2 * HIN;
    constexpr int NPB = (B_ * HIN * HIN) / 256;
    int pb = blockIdx.x % NPB;
    int z  = blockIdx.x / NPB;
    int og = z % (COUT / G);
    int ry = z / (COUT / G);
    int o0 = og * G;
    int rem = pb * 256 + threadIdx.x;
    int b   = rem / (HIN * HIN);
    int pix = rem % (HIN * HIN);
    int py = pix / HIN, px = pix % HIN;
    const float* xb = xp + ((size_t)b * CIN) * (HP * HP) + (py + ry) * HP + px;
    const float4* w4 = (const float4*)wr;
    float acc0[G], acc1[G];
    #pragma unroll
    for (int o = 0; o < G; ++o) { acc0[o] = 0.f; acc1[o] = 0.f; }
    float f00 = xb[0], f01 = xb[1], f02 = xb[2];
    float f10 = xb[HP], f11 = xb[HP + 1], f12 = xb[HP + 2];
    for (int ci = 0; ci < CIN; ++ci) {
        int cn = (ci + 1 < CIN) ? (ci + 1) : (CIN - 1);
        const float* xn = xb + (size_t)cn * (HP * HP);
        float n00 = xn[0], n01 = xn[1], n02 = xn[2];
        float n10 = xn[HP], n11 = xn[HP + 1], n12 = xn[HP + 2];
        const float4* w0 = w4 + ((size_t)(2 * ry) * CIN + ci) * COUT + o0;
        const float4* w1 = w0 + (size_t)CIN * COUT;
        #pragma unroll
        for (int o = 0; o < G; ++o) {
            float4 W0 = w0[o], W1 = w1[o];
            acc0[o] += f00 * W0.x + f01 * W0.y + f10 * W0.z + f11 * W0.w;
            acc1[o] += f01 * W1.x + f02 * W1.y + f11 * W1.z + f12 * W1.w;
        }
        f00 = n00; f01 = n01; f02 = n02; f10 = n10; f11 = n11; f12 = n12;
    }
    int oy = 2 * py + ry;
    #pragma unroll
    for (int o = 0; o < G; ++o) {
        float bb = bias[o0 + o];
        float2 v; v.x = acc0[o] + bb; v.y = acc1[o] + bb;
        *(float2*)(out + ((size_t)(b * COUT + o0 + o) * HO + oy) * HO + 2 * px) = v;
    }
}

// ---------------------------------------------------------------------------
// spatial LN planar -> planar padded (L2 output)
// ---------------------------------------------------------------------------
template<int H>
__global__ void __launch_bounds__(256) k_ln_pad(const float* __restrict__ cin,
                                                const float* __restrict__ g,
                                                const float* __restrict__ bv,
                                                float* __restrict__ xp)
{
    constexpr int HW = H * H;
    constexpr int HP = H + 2;
    constexpr int HWP = HP * HP;
    size_t plane = blockIdx.x;
    const float* src = cin + plane * HW;
    float* dst = xp + plane * HWP;
    int t = threadIdx.x;
    float s = 0.f, q = 0.f;
    for (int i = t; i < HW; i += 256) {
        float v = src[i];
        s += v; q += v * v;
    }
    #pragma unroll
    for (int off = 32; off; off >>= 1) {
        s += __shfl_xor(s, off);
        q += __shfl_xor(q, off);
    }
    __shared__ float rs[8];
    int wave = t >> 6, lane = t & 63;
    if (lane == 0) { rs[wave] = s; rs[4 + wave] = q; }
    __syncthreads();
    float st = rs[0] + rs[1] + rs[2] + rs[3];
    float qt = rs[4] + rs[5] + rs[6] + rs[7];
    float mu = st / (float)HW;
    float rstd = rsqrtf(qt / (float)HW - mu * mu + 1e-5f);
    for (int i = t; i < HWP; i += 256) {
        int py = i / HP, px = i % HP;
        float v = 0.f;
        if (py >= 1 && py <= H && px >= 1 && px <= H) {
            int j = (py - 1) * H + (px - 1);
            float u = (src[j] - mu) * rstd * g[j] + bv[j];
            v = u / (1.f + expf(-u));
        }
        dst[i] = v;
    }
}

// ---------------------------------------------------------------------------
// in-place spatial LN + affine + silu (L3 output)
// ---------------------------------------------------------------------------
template<int HW>
__global__ void __launch_bounds__(256) k_ln_spatial(float* __restrict__ f,
                                                    const float* __restrict__ g,
                                                    const float* __restrict__ bv)
{
    size_t base = (size_t)blockIdx.x * HW;
    int t = threadIdx.x;
    float s = 0.f, q = 0.f;
    for (int i = t; i < HW; i += 256) {
        float v = f[base + i];
        s += v; q += v * v;
    }
    #pragma unroll
    for (int off = 32; off; off >>= 1) {
        s += __shfl_xor(s, off);
        q += __shfl_xor(q, off);
    }
    __shared__ float rs[8];
    int wave = t >> 6, lane = t & 63;
    if (lane == 0) { rs[wave] = s; rs[4 + wave] = q; }
    __syncthreads();
    float st = rs[0] + rs[1] + rs[2] + rs[3];
    float qt = rs[4] + rs[5] + rs[6] + rs[7];
    float mu = st / (float)HW;
    float rstd = rsqrtf(qt / (float)HW - mu * mu + 1e-5f);
    for (int i = t; i < HW; i += 256) {
        float v = (f[base + i] - mu) * rstd * g[i] + bv[i];
        f[base + i] = v / (1.f + expf(-v));
    }
}

// ---------------------------------------------------------------------------
// final convT 12->1 (r4-measured 2-parity version)
// ---------------------------------------------------------------------------
__global__ void __launch_bounds__(256) k_conv_final(const float* __restrict__ x,
                                                    const float* __restrict__ wr,
                                                    const float* __restrict__ bias,
                                                    float* __restrict__ out)
{
    constexpr int HIN = 112, CIN = 12, HP2 = 12544;
    constexpr int NPB = (B_ * HIN * HIN) / 256;
    int pb = blockIdx.x % NPB;
    int ry = blockIdx.x / NPB;
    int rem = pb * 256 + threadIdx.x;
    int b   = rem / (HIN * HIN);
    int pix = rem % (HIN * HIN);
    int py = pix / HIN, px = pix % HIN;
    int r0 = py + ry - 1, r1 = r0 + 1;
    bool my0 = r0 >= 0, my1 = r1 < HIN;
    bool mx0 = px >= 1, mx2 = px + 1 < HIN;
    const float* xb = x + (size_t)b * CIN * HP2;
    const float4* w4 = (const float4*)wr;
    float acc0 = 0.f, acc1 = 0.f;
    #pragma unroll
    for (int ci = 0; ci < CIN; ++ci) {
        const float* xc = xb + ci * HP2;
        const float* xr0 = xc + r0 * HIN + px;
        const float* xr1 = xc + r1 * HIN + px;
        float g00 = (my0 && mx0) ? xr0[-1] : 0.f;
        float g01 = my0 ? xr0[0] : 0.f;
        float g02 = (my0 && mx2) ? xr0[1] : 0.f;
        float g10 = (my1 && mx0) ? xr1[-1] : 0.f;
        float g11 = my1 ? xr1[0] : 0.f;
        float g12 = (my1 && mx2) ? xr1[1] : 0.f;
        float4 W0 = w4[(2 * ry) * CIN + ci];
        float4 W1 = w4[(2 * ry + 1) * CIN + ci];
        acc0 += g00 * W0.x + g01 * W0.y + g10 * W0.z + g11 * W0.w;
        acc1 += g01 * W1.x + g02 * W1.y + g11 * W1.z + g12 * W1.w;
    }
    float bb = bias[0];
    float u0 = acc0 + bb, u1 = acc1 + bb;
    u0 = u0 / (1.f + expf(-u0));
    u1 = u1 / (1.f + expf(-u1));
    float2 v;
    v.x = fminf(fmaxf(u0, 0.f), 1.f);
    v.y = fminf(fmaxf(u1, 0.f), 1.f);
    int oy = 2 * py + ry;
    *(float2*)(out + (size_t)b * 50176 + oy * 224 + 2 * px) = v;
}

// ---------------------------------------------------------------------------
// launch
// ---------------------------------------------------------------------------
extern "C" void kernel_launch(void* const* d_in, const int* in_sizes, int n_in,
                              void* d_out, int out_size, void* d_ws, size_t ws_size,
                              hipStream_t stream)
{
    const float* x       = (const float*)d_in[0];
    const float* ts      = (const float*)d_in[1];
    const float* Wp      = (const float*)d_in[2];
    const float* bp      = (const float*)d_in[3];
    const float* Wt1     = (const float*)d_in[4];
    const float* bt1     = (const float*)d_in[5];
    const float* Wt2     = (const float*)d_in[6];
    const float* bt2     = (const float*)d_in[7];
    const float* a0_g    = (const float*)d_in[8];
    const float* a0_b    = (const float*)d_in[9];
    const float* a0_Wqkv = (const float*)d_in[10];
    const float* a0_bqkv = (const float*)d_in[11];
    const float* a0_Wo   = (const float*)d_in[12];
    const float* a0_bo   = (const float*)d_in[13];
    const float* a1_g    = (const float*)d_in[14];
    const float* a1_b    = (const float*)d_in[15];
    const float* a1_Wqkv = (const float*)d_in[16];
    const float* a1_bqkv = (const float*)d_in[17];
    const float* a1_Wo   = (const float*)d_in[18];
    const float* a1_bo   = (const float*)d_in[19];
    const float* Wm0     = (const float*)d_in[20];
    const float* bm0     = (const float*)d_in[21];
    const float* Wm1     = (const float*)d_in[22];
    const float* bm1     = (const float*)d_in[23];
    const float* Wm2     = (const float*)d_in[24];
    const float* bm2     = (const float*)d_in[25];
    const float* Wd1     = (const float*)d_in[26];
    const float* bd1     = (const float*)d_in[27];
    const float* l1g     = (const float*)d_in[28];
    const float* l1b     = (const float*)d_in[29];
    const float* Wd2     = (const float*)d_in[30];
    const float* bd2     = (const float*)d_in[31];
    const float* l2g     = (const float*)d_in[32];
    const float* l2b     = (const float*)d_in[33];
    const float* Wd3     = (const float*)d_in[34];
    const float* bd3     = (const float*)d_in[35];
    const float* l3g     = (const float*)d_in[36];
    const float* l3b     = (const float*)d_in[37];
    const float* Wd4     = (const float*)d_in[38];
    const float* bd4     = (const float*)d_in[39];
    float* out = (float*)d_out;

    // arena (floats); R = 25088*96
    const size_t R = 2408448;
    float* ws   = (float*)d_ws;
    float* tvec = ws;                          // 96
    float* p0   = ws + 512;                    // R
    float* h    = ws + 512 + R;                // R
    float* qkvb = ws + 512 + 2 * R;            // 3R
    float* ob   = ws + 512 + 5 * R;            // R
    float* p1   = ws + 512 + 6 * R;            // R
    float* part = ws + 512 + 7 * R;            // attn partials (aliases XP2/XP3)
    // decoder aliases:
    _Float16* xinh = (_Float16*)(ws + 512 + 2 * R);   // f16 NHWC (qkv region)
    float* C1   = ws + 512 + 5 * R;            // NHWC fp32 [b][28][28][48] (ob+p1)
    float* XP2  = ws + 512 + 7 * R;            // planar padded [b*48][30][30]
    float* C2   = ws + 512;                    // (p0..qkv regions)
    float* XP3  = ws + 512 + 7 * R + 5529600;
    float* C3   = ws + 512;                    // (p0..XP2 regions)
    float* Wr   = ws + 512 + 7 * R + 5529600 + 10334208;  // 96,960 floats
    _Float16* WH = (_Float16*)(Wr + 96960);                // 101,376 halves = 50,688 floats
    _Float16* Wc = (_Float16*)Wr;              // conv1 f16 B-weights (dead L1 slice)
    float* stat = Wr + 96960 + 50688;          // 12,288 floats (L1 LN stats)
    const size_t NEED = (512 + 7 * R + 5529600 + 10334208 + 96960 + 50688 + 12288 + 16)
                        * sizeof(float);
    if (ws_size < NEED) return;

    _Float16* WHqkv0 = WH;
    _Float16* WHqkv1 = WH + 27648;
    _Float16* WHwo0  = WH + 55296;
    _Float16* WHwo1  = WH + 64512;
    _Float16* WHwm0  = WH + 73728;
    _Float16* WHwm1  = WH + 82944;
    _Float16* WHwm2  = WH + 92160;

    k_time<<<1, 128, 0, stream>>>(ts, Wt1, bt1, Wt2, bt2, tvec);
    k_repack<<<379, 256, 0, stream>>>(Wd1, Wd2, Wd3, Wd4, Wr);
    k_wcvtc<<<288, 256, 0, stream>>>(Wd1, Wc);
    k_wcvt<<<396, 256, 0, stream>>>(a0_Wqkv, a1_Wqkv, a0_Wo, a1_Wo,
                                    Wm0, Wm1, Wm2, WH);
    k_patch_mfma<<<M_ROWS / 64, 256, 0, stream>>>(x, Wp, bp, p0);

    // MHSA block 0
    k_ln_row<<<1024, 256, 0, stream>>>(p0, a0_g, a0_b, h, M_ROWS);
    k_gemm_mfma<3, false, false, false, false><<<M_ROWS / 64, 256, 0, stream>>>(
        h, WHqkv0, a0_bqkv, nullptr, nullptr, qkvb, nullptr);
    k_attn_part<<<B_ * 4 * KS, 256, 0, stream>>>(qkvb, part);
    k_attn_comb<<<(B_ * 4 * NPATCH) / 256, 256, 0, stream>>>(part, ob);
    k_gemm_mfma<1, false, true, false, false><<<M_ROWS / 64, 256, 0, stream>>>(
        ob, WHwo0, a0_bo, p0, nullptr, p1, nullptr);

    // MHSA block 1 (+time)
    k_ln_row<<<1024, 256, 0, stream>>>(p1, a1_g, a1_b, h, M_ROWS);
    k_gemm_mfma<3, false, false, false, false><<<M_ROWS / 64, 256, 0, stream>>>(
        h, WHqkv1, a1_bqkv, nullptr, nullptr, qkvb, nullptr);
    k_attn_part<<<B_ * 4 * KS, 256, 0, stream>>>(qkvb, part);
    k_attn_comb<<<(B_ * 4 * NPATCH) / 256, 256, 0, stream>>>(part, ob);
    k_gemm_mfma<1, false, true, true, false><<<M_ROWS / 64, 256, 0, stream>>>(
        ob, WHwo1, a1_bo, p1, tvec, p0, nullptr);

    // qkv region free: zero xinh borders before MLP3 writes interior
    k_zb_h<<<2880, 256, 0, stream>>>(xinh);

    // MLP x3 (silu); last writes f16 NHWC padded xinh
    k_gemm_mfma<1, true, false, false, false><<<M_ROWS / 64, 256, 0, stream>>>(
        p0, WHwm0, bm0, nullptr, nullptr, p1, nullptr);
    k_gemm_mfma<1, true, false, false, false><<<M_ROWS / 64, 256, 0, stream>>>(
        p1, WHwm1, bm1, nullptr, nullptr, p0, nullptr);
    k_gemm_mfma<1, true, false, false, true><<<M_ROWS / 64, 256, 0, stream>>>(
        p0, WHwm2, bm2, nullptr, nullptr, nullptr, xinh);

    // decoder: L1 MFMA, parallel LN bridge, then r5-measured planar convs
    k_conv1<<<M_ROWS / 64, 256, 0, stream>>>(xinh, Wc, bd1, C1);
    k_ln1_stats<<<1536, 256, 0, stream>>>(C1, stat);
    k_ln1_apply<<<21600, 256, 0, stream>>>(C1, stat, l1g, l1b, XP2);
    k_convg<48, 28, 24, 8><<<2 * 3 * 392, 256, 0, stream>>>(XP2, Wr + 73728, bd2, C2);
    k_ln_pad<56><<<B_ * 24, 256, 0, stream>>>(C2, l2g, l2b, XP3);
    k_convg<24, 56, 12, 12><<<2 * 1 * 1568, 256, 0, stream>>>(XP3, Wr + 92160, bd3, C3);
    k_ln_spatial<12544><<<B_ * 12, 256, 0, stream>>>(C3, l3g, l3b);
    k_conv_final<<<2 * 6272, 256, 0, stream>>>(C3, Wr + 96768, bd4, out);
}